// Round 3
// baseline (582.075 us; speedup 1.0000x reference)
//
#include <hip/hip_runtime.h>

#define N_ 8
#define C_ 256
#define HW_ 4096

typedef __bf16 bf16x8 __attribute__((ext_vector_type(8)));
typedef float f32x4 __attribute__((ext_vector_type(4)));
typedef unsigned short u16x8 __attribute__((ext_vector_type(8)));

#define MFMA(a, b, c) __builtin_amdgcn_mfma_f32_16x16x32_bf16(a, b, c, 0, 0, 0)

static __device__ __forceinline__ unsigned short f2bf(float f) {
    union { float f; unsigned int u; } v; v.f = f;
    unsigned int u = v.u;
    return (unsigned short)((u + 0x7FFFu + ((u >> 16) & 1u)) >> 16);  // RNE
}

static __device__ __forceinline__ bf16x8 pack_bf8(float4 a, float4 b) {
    u16x8 t;
    t[0] = f2bf(a.x); t[1] = f2bf(a.y); t[2] = f2bf(a.z); t[3] = f2bf(a.w);
    t[4] = f2bf(b.x); t[5] = f2bf(b.y); t[6] = f2bf(b.z); t[7] = f2bf(b.w);
    return __builtin_bit_cast(bf16x8, t);
}

// ---------------------------------------------------------------------------
// Kernel 1: theta/phi/g 1x1 convs.  x:[N,C,HW] f32 -> thetaT/phiT:[N,HW,C] bf16
// (theta pre-scaled by C^-0.5), gC:[N,C,HW] bf16 WITHOUT b_g (b_g contributes
// a per-channel constant to p via softmax-sum-1; BatchNorm absorbs it exactly;
// dropping it keeps stored-O magnitudes small -> less bf16 quantization).
// ---------------------------------------------------------------------------
__global__ __launch_bounds__(256) void qkv_kernel(
    const float* __restrict__ x,
    const float* __restrict__ w_theta, const float* __restrict__ b_theta,
    const float* __restrict__ w_phi,   const float* __restrict__ b_phi,
    const float* __restrict__ w_g,     const float* __restrict__ b_g,
    unsigned short* __restrict__ thetaT, unsigned short* __restrict__ phiT,
    unsigned short* __restrict__ gC)
{
    __shared__ unsigned short xT[64 * 264];   // x tile transposed [hw][c], pad 264
    const int tid = threadIdx.x;
    const int hw0 = blockIdx.x * 64;
    const int n   = blockIdx.y;
    const float* xb = x + (size_t)n * C_ * HW_;
    for (int i = 0; i < 16; ++i) {
        int e   = tid + i * 256;          // 4096 float4 chunks (256c x 16)
        int c   = e >> 4;
        int hw4 = (e & 15) << 2;
        float4 v = *reinterpret_cast<const float4*>(xb + (size_t)c * HW_ + hw0 + hw4);
        xT[(hw4 + 0) * 264 + c] = f2bf(v.x);
        xT[(hw4 + 1) * 264 + c] = f2bf(v.y);
        xT[(hw4 + 2) * 264 + c] = f2bf(v.z);
        xT[(hw4 + 3) * 264 + c] = f2bf(v.w);
    }
    __syncthreads();

    const int w = tid >> 6, lane = tid & 63;
    const int g16 = lane >> 4, l16 = lane & 15;

    const float* Wp[3] = { w_theta, w_phi, w_g };
    const float* Bp[3] = { b_theta, b_phi, b_g };

    for (int ot = 0; ot < 4; ++ot) {
        const int oB    = ot * 64;
        const int wrow  = oB + w * 16 + l16;       // A-frag row (o)
        const int orow0 = oB + w * 16 + g16 * 4;   // D rows base (o)
        #pragma unroll
        for (int wt = 0; wt < 3; ++wt) {
            const float* W = Wp[wt];
            bf16x8 aw[8];
            #pragma unroll
            for (int kk = 0; kk < 8; ++kk) {
                const float* wp = W + (size_t)wrow * C_ + kk * 32 + g16 * 8;
                float4 f0 = *reinterpret_cast<const float4*>(wp);
                float4 f1 = *reinterpret_cast<const float4*>(wp + 4);
                aw[kk] = pack_bf8(f0, f1);
            }
            f32x4 acc[4];
            #pragma unroll
            for (int cb = 0; cb < 4; ++cb) {
                acc[cb][0] = 0.f; acc[cb][1] = 0.f; acc[cb][2] = 0.f; acc[cb][3] = 0.f;
            }
            #pragma unroll
            for (int kk = 0; kk < 8; ++kk) {
                #pragma unroll
                for (int cb = 0; cb < 4; ++cb) {
                    bf16x8 b = *reinterpret_cast<const bf16x8*>(
                        &xT[(cb * 16 + l16) * 264 + kk * 32 + g16 * 8]);
                    acc[cb] = MFMA(aw[kk], b, acc[cb]);
                }
            }
            const float* bp = Bp[wt];
            float bj0 = bp[orow0], bj1 = bp[orow0 + 1], bj2 = bp[orow0 + 2], bj3 = bp[orow0 + 3];
            if (wt == 2) { bj0 = 0.f; bj1 = 0.f; bj2 = 0.f; bj3 = 0.f; }  // drop b_g (BN-absorbed)
            if (wt < 2) {
                unsigned short* dst = (wt == 0) ? thetaT : phiT;
                const float sc = (wt == 0) ? 0.0625f : 1.0f;   // fold C^-0.5 into theta
                #pragma unroll
                for (int cb = 0; cb < 4; ++cb) {
                    int hw = hw0 + cb * 16 + l16;
                    ushort4 pk;
                    pk.x = f2bf((acc[cb][0] + bj0) * sc);
                    pk.y = f2bf((acc[cb][1] + bj1) * sc);
                    pk.z = f2bf((acc[cb][2] + bj2) * sc);
                    pk.w = f2bf((acc[cb][3] + bj3) * sc);
                    *reinterpret_cast<ushort4*>(&dst[((size_t)n * HW_ + hw) * C_ + orow0]) = pk;
                }
            } else {
                #pragma unroll
                for (int cb = 0; cb < 4; ++cb) {
                    int hw = hw0 + cb * 16 + l16;
                    gC[((size_t)n * C_ + orow0 + 0) * HW_ + hw] = f2bf(acc[cb][0]);
                    gC[((size_t)n * C_ + orow0 + 1) * HW_ + hw] = f2bf(acc[cb][1]);
                    gC[((size_t)n * C_ + orow0 + 2) * HW_ + hw] = f2bf(acc[cb][2]);
                    gC[((size_t)n * C_ + orow0 + 3) * HW_ + hw] = f2bf(acc[cb][3]);
                }
            }
        }
    }
}

// ---------------------------------------------------------------------------
// Kernel 2: flash attention.  S = thetaT . phiT^T (scale folded), online
// softmax over 4096 kv, O += P . V  (V = gC used as [C,HW] -> B-operand).
// Block = 64 q-rows (4 waves x 16 rows), kv tile = 64.  Out tpgT:[N,HW,C] bf16.
// ---------------------------------------------------------------------------
__global__ __launch_bounds__(256, 2) void attn_kernel(
    const unsigned short* __restrict__ thetaT,
    const unsigned short* __restrict__ phiT,
    const unsigned short* __restrict__ gC,
    unsigned short* __restrict__ tpgT)
{
    __shared__ unsigned short Kl[64 * 264];    // phiT tile [kv][c]   pad 264
    __shared__ unsigned short Vl[256 * 72];    // gC tile   [c][kv]   pad 72
    __shared__ unsigned short Pl[4 * 16 * 72]; // per-wave P tile [16][64] pad 72
    const int tid = threadIdx.x;
    const int h0  = blockIdx.x * 64;
    const int n   = blockIdx.y;
    const int w = tid >> 6, lane = tid & 63, g16 = lane >> 4, l16 = lane & 15;

    // Q fragments (row = h, k = c), 16 rows per wave, kept in regs
    bf16x8 q[8];
    {
        const unsigned short* qp = thetaT + ((size_t)n * HW_ + h0 + w * 16 + l16) * C_;
        #pragma unroll
        for (int kk = 0; kk < 8; ++kk)
            q[kk] = *reinterpret_cast<const bf16x8*>(qp + kk * 32 + g16 * 8);
    }
    f32x4 oacc[16];
    #pragma unroll
    for (int i = 0; i < 16; ++i) { oacc[i][0]=0.f; oacc[i][1]=0.f; oacc[i][2]=0.f; oacc[i][3]=0.f; }
    float mj[4] = { -1e30f, -1e30f, -1e30f, -1e30f };
    float lj[4] = { 0.f, 0.f, 0.f, 0.f };

    const unsigned short* Kb = phiT + (size_t)n * HW_ * C_;
    const unsigned short* Vb = gC   + (size_t)n * C_ * HW_;
    unsigned short* Pw = Pl + w * 16 * 72;

    for (int t = 0; t < 64; ++t) {
        __syncthreads();
        // stage K tile: 64 rows x 256 c  (2048 x 16B)
        for (int i = 0; i < 8; ++i) {
            int e = tid + i * 256;
            int r = e >> 5, c8 = (e & 31) << 3;
            *reinterpret_cast<uint4*>(&Kl[r * 264 + c8]) =
                *reinterpret_cast<const uint4*>(Kb + ((size_t)t * 64 + r) * C_ + c8);
        }
        // stage V tile: 256 rows x 64 kv (2048 x 16B)
        for (int i = 0; i < 8; ++i) {
            int e = tid + i * 256;
            int c = e >> 3, o8 = (e & 7) << 3;
            *reinterpret_cast<uint4*>(&Vl[c * 72 + o8]) =
                *reinterpret_cast<const uint4*>(Vb + (size_t)c * HW_ + t * 64 + o8);
        }
        __syncthreads();

        // S = Q K^T : 16x64 per wave
        f32x4 s[4];
        #pragma unroll
        for (int cb = 0; cb < 4; ++cb) { s[cb][0]=0.f; s[cb][1]=0.f; s[cb][2]=0.f; s[cb][3]=0.f; }
        #pragma unroll
        for (int kk = 0; kk < 8; ++kk) {
            #pragma unroll
            for (int cb = 0; cb < 4; ++cb) {
                bf16x8 b = *reinterpret_cast<const bf16x8*>(
                    &Kl[(cb * 16 + l16) * 264 + kk * 32 + g16 * 8]);
                s[cb] = MFMA(q[kk], b, s[cb]);
            }
        }
        // online softmax; D row r = 4*g16 + j, col = cb*16 + l16
        #pragma unroll
        for (int j = 0; j < 4; ++j) {
            float v0 = fmaxf(fmaxf(s[0][j], s[1][j]), fmaxf(s[2][j], s[3][j]));
            v0 = fmaxf(v0, __shfl_xor(v0, 1));
            v0 = fmaxf(v0, __shfl_xor(v0, 2));
            v0 = fmaxf(v0, __shfl_xor(v0, 4));
            v0 = fmaxf(v0, __shfl_xor(v0, 8));
            float mn = fmaxf(mj[j], v0);
            float sc = __expf(mj[j] - mn);
            float rs = 0.f;
            int r = g16 * 4 + j;
            #pragma unroll
            for (int cb = 0; cb < 4; ++cb) {
                float pv = __expf(s[cb][j] - mn);
                rs += pv;
                Pw[r * 72 + cb * 16 + l16] = f2bf(pv);
            }
            rs += __shfl_xor(rs, 1);
            rs += __shfl_xor(rs, 2);
            rs += __shfl_xor(rs, 4);
            rs += __shfl_xor(rs, 8);
            lj[j] = lj[j] * sc + rs;
            mj[j] = mn;
            #pragma unroll
            for (int ncb = 0; ncb < 16; ++ncb) oacc[ncb][j] *= sc;
        }
        // O += P V   (A = P from LDS, B = Vl rows c, k = kv)
        #pragma unroll
        for (int k2 = 0; k2 < 2; ++k2) {
            bf16x8 pa = *reinterpret_cast<const bf16x8*>(&Pw[l16 * 72 + k2 * 32 + g16 * 8]);
            #pragma unroll
            for (int ncb = 0; ncb < 16; ++ncb) {
                bf16x8 vb = *reinterpret_cast<const bf16x8*>(
                    &Vl[(ncb * 16 + l16) * 72 + k2 * 32 + g16 * 8]);
                oacc[ncb] = MFMA(pa, vb, oacc[ncb]);
            }
        }
    }
    // normalize + write tpgT[hw][c]
    #pragma unroll
    for (int j = 0; j < 4; ++j) {
        float inv = 1.0f / lj[j];
        int h = h0 + w * 16 + g16 * 4 + j;
        unsigned short* op = tpgT + ((size_t)n * HW_ + h) * C_;
        #pragma unroll
        for (int ncb = 0; ncb < 16; ++ncb)
            op[ncb * 16 + l16] = f2bf(oacc[ncb][j] * inv);
    }
}

// ---------------------------------------------------------------------------
// Kernel 3: p = w_out . tpg + b_out  -> p:[N,C,HW] f32, plus per-channel
// partial sum/sumsq (atomics) for batchnorm stats.
// ---------------------------------------------------------------------------
__global__ __launch_bounds__(256) void outconv_kernel(
    const unsigned short* __restrict__ tpgT,
    const float* __restrict__ w_out, const float* __restrict__ b_out,
    float* __restrict__ p, float* __restrict__ bnsum, float* __restrict__ bnsumsq)
{
    __shared__ unsigned short Bl[64 * 264];
    const int tid = threadIdx.x;
    const int hw0 = blockIdx.x * 64;
    const int n   = blockIdx.y;
    const unsigned short* Tb = tpgT + (size_t)n * HW_ * C_;
    for (int i = 0; i < 8; ++i) {
        int e = tid + i * 256;
        int r = e >> 5, c8 = (e & 31) << 3;
        *reinterpret_cast<uint4*>(&Bl[r * 264 + c8]) =
            *reinterpret_cast<const uint4*>(Tb + ((size_t)hw0 + r) * C_ + c8);
    }
    __syncthreads();
    const int w = tid >> 6, lane = tid & 63, g16 = lane >> 4, l16 = lane & 15;

    for (int ot = 0; ot < 4; ++ot) {
        const int oB   = ot * 64;
        const int wrow = oB + w * 16 + l16;
        bf16x8 aw[8];
        #pragma unroll
        for (int kk = 0; kk < 8; ++kk) {
            const float* wp = w_out + (size_t)wrow * C_ + kk * 32 + g16 * 8;
            float4 f0 = *reinterpret_cast<const float4*>(wp);
            float4 f1 = *reinterpret_cast<const float4*>(wp + 4);
            aw[kk] = pack_bf8(f0, f1);
        }
        f32x4 acc[4];
        #pragma unroll
        for (int cb = 0; cb < 4; ++cb) { acc[cb][0]=0.f; acc[cb][1]=0.f; acc[cb][2]=0.f; acc[cb][3]=0.f; }
        #pragma unroll
        for (int kk = 0; kk < 8; ++kk) {
            #pragma unroll
            for (int cb = 0; cb < 4; ++cb) {
                bf16x8 b = *reinterpret_cast<const bf16x8*>(
                    &Bl[(cb * 16 + l16) * 264 + kk * 32 + g16 * 8]);
                acc[cb] = MFMA(aw[kk], b, acc[cb]);
            }
        }
        const int orow0 = oB + w * 16 + g16 * 4;
        float bj[4] = { b_out[orow0], b_out[orow0 + 1], b_out[orow0 + 2], b_out[orow0 + 3] };
        float s1[4] = {0.f,0.f,0.f,0.f}, s2[4] = {0.f,0.f,0.f,0.f};
        #pragma unroll
        for (int cb = 0; cb < 4; ++cb) {
            #pragma unroll
            for (int j = 0; j < 4; ++j) {
                float pv = acc[cb][j] + bj[j];
                p[((size_t)n * C_ + orow0 + j) * HW_ + hw0 + cb * 16 + l16] = pv;
                s1[j] += pv;
                s2[j] += pv * pv;
            }
        }
        #pragma unroll
        for (int j = 0; j < 4; ++j) {
            float a1 = s1[j], a2 = s2[j];
            a1 += __shfl_xor(a1, 1); a2 += __shfl_xor(a2, 1);
            a1 += __shfl_xor(a1, 2); a2 += __shfl_xor(a2, 2);
            a1 += __shfl_xor(a1, 4); a2 += __shfl_xor(a2, 4);
            a1 += __shfl_xor(a1, 8); a2 += __shfl_xor(a2, 8);
            if (l16 == 0) {
                atomicAdd(&bnsum[orow0 + j], a1);
                atomicAdd(&bnsumsq[orow0 + j], a2);
            }
        }
    }
}

// ---------------------------------------------------------------------------
// Kernel 4: finalize BN stats -> per-channel scale/shift
// ---------------------------------------------------------------------------
__global__ void bnfin_kernel(const float* __restrict__ bnsum,
                             const float* __restrict__ bnsumsq,
                             const float* __restrict__ gamma,
                             const float* __restrict__ beta,
                             float* __restrict__ bnscale, float* __restrict__ bnshift)
{
    int c = threadIdx.x;
    const float cnt = (float)(N_ * HW_);
    float mean = bnsum[c] / cnt;
    float var  = bnsumsq[c] / cnt - mean * mean;
    float inv  = rsqrtf(var + 1e-5f);
    float sc   = gamma[c] * inv;
    bnscale[c] = sc;
    bnshift[c] = beta[c] - mean * sc;
}

// ---------------------------------------------------------------------------
// Kernel 5: z = (1-wg)*x + wg*(p*scale + shift)
// ---------------------------------------------------------------------------
__global__ __launch_bounds__(256) void final_kernel(
    const float* __restrict__ x, const float* __restrict__ p,
    const float* __restrict__ bnscale, const float* __restrict__ bnshift,
    const float* __restrict__ wgate, float* __restrict__ out)
{
    const float wg = *wgate;
    const float og = 1.0f - wg;
    const int total = N_ * C_ * HW_ / 4;   // float4 count
    for (int e = blockIdx.x * 256 + threadIdx.x; e < total; e += gridDim.x * 256) {
        int c = (e >> 10) & 255;           // 1024 float4 per (n,c) row
        float sc = bnscale[c], sh = bnshift[c];
        float4 xv = reinterpret_cast<const float4*>(x)[e];
        float4 pv = reinterpret_cast<const float4*>(p)[e];
        float4 z;
        z.x = og * xv.x + wg * (pv.x * sc + sh);
        z.y = og * xv.y + wg * (pv.y * sc + sh);
        z.z = og * xv.z + wg * (pv.z * sc + sh);
        z.w = og * xv.w + wg * (pv.w * sc + sh);
        reinterpret_cast<float4*>(out)[e] = z;
    }
}

extern "C" void kernel_launch(void* const* d_in, const int* in_sizes, int n_in,
                              void* d_out, int out_size, void* d_ws, size_t ws_size,
                              hipStream_t stream)
{
    (void)in_sizes; (void)n_in; (void)out_size; (void)ws_size;
    const float* x       = (const float*)d_in[0];
    const float* w_theta = (const float*)d_in[1];
    const float* b_theta = (const float*)d_in[2];
    const float* w_phi   = (const float*)d_in[3];
    const float* b_phi   = (const float*)d_in[4];
    const float* w_g     = (const float*)d_in[5];
    const float* b_g     = (const float*)d_in[6];
    const float* w_out   = (const float*)d_in[7];
    const float* b_out   = (const float*)d_in[8];
    const float* gamma   = (const float*)d_in[9];
    const float* beta    = (const float*)d_in[10];
    const float* wgate   = (const float*)d_in[11];
    float* out = (float*)d_out;

    char* ws = (char*)d_ws;
    unsigned short* thetaT = (unsigned short*)(ws + 0);           // 16 MiB
    unsigned short* phiT   = (unsigned short*)(ws + 16777216);    // 16 MiB
    unsigned short* gC     = (unsigned short*)(ws + 33554432);    // 16 MiB
    unsigned short* tpgT   = (unsigned short*)(ws + 50331648);    // 16 MiB
    float* p       = (float*)(ws + 0);            // 32 MiB, aliases dead theta/phi
    float* bnsum   = (float*)(ws + 67108864);
    float* bnsumsq = (float*)(ws + 67108864 + 1024);
    float* bnscale = (float*)(ws + 67108864 + 2048);
    float* bnshift = (float*)(ws + 67108864 + 3072);

    hipMemsetAsync(bnsum, 0, 2048, stream);   // zero sum+sumsq

    qkv_kernel<<<dim3(64, 8), 256, 0, stream>>>(
        x, w_theta, b_theta, w_phi, b_phi, w_g, b_g, thetaT, phiT, gC);
    attn_kernel<<<dim3(64, 8), 256, 0, stream>>>(thetaT, phiT, gC, tpgT);
    outconv_kernel<<<dim3(64, 8), 256, 0, stream>>>(tpgT, w_out, b_out, p, bnsum, bnsumsq);
    bnfin_kernel<<<1, 256, 0, stream>>>(bnsum, bnsumsq, gamma, beta, bnscale, bnshift);
    final_kernel<<<dim3(2048), 256, 0, stream>>>(x, p, bnscale, bnshift, wgate, out);
}